// Round 8
// baseline (286.599 us; speedup 1.0000x reference)
//
#include <hip/hip_runtime.h>

typedef __attribute__((ext_vector_type(8))) short short8_t;
typedef __attribute__((ext_vector_type(4))) short short4_t;
typedef __attribute__((ext_vector_type(4))) float float4_t;

#define MFMA16(a, b, c) __builtin_amdgcn_mfma_f32_16x16x32_bf16((a), (b), (c), 0, 0, 0)
#define GLOAD_LDS16(g, l)                                                   \
  __builtin_amdgcn_global_load_lds(                                         \
      (const __attribute__((address_space(1))) void*)(g),                   \
      (__attribute__((address_space(3))) void*)(l), 16, 0, 0)

// fp32 -> bf16 round-to-nearest-even (finite inputs only)
static __device__ __forceinline__ unsigned short f2b(float f) {
  unsigned int x = __builtin_bit_cast(unsigned int, f);
  x = (x + 0x7fffu + ((x >> 16) & 1u)) >> 16;
  return (unsigned short)x;
}

// packed fp32x2 -> bf16x2, RNE (hardware v_cvt_pk_bf16_f32; same bits as f2b
// for all finite inputs)
static __device__ __forceinline__ unsigned int cvtpk(float lo, float hi) {
  unsigned int r;
  asm("v_cvt_pk_bf16_f32 %0, %1, %2" : "=v"(r) : "v"(lo), "v"(hi));
  return r;
}

static __device__ __forceinline__ short8_t pack8(float4 x, float4 y) {
  short8_t v;
  v[0] = (short)f2b(x.x); v[1] = (short)f2b(x.y);
  v[2] = (short)f2b(x.z); v[3] = (short)f2b(x.w);
  v[4] = (short)f2b(y.x); v[5] = (short)f2b(y.y);
  v[6] = (short)f2b(y.z); v[7] = (short)f2b(y.w);
  return v;
}

// ---------------------------------------------------------------------------
// Kernel 1: MT[j][d] = (1/32) * sum_k binding[j][k] * Wq[d][k]   (bf16 out)
// ---------------------------------------------------------------------------
__global__ __launch_bounds__(256, 2) void mt_kernel(
    const float* __restrict__ Wq, const float* __restrict__ binding,
    short* __restrict__ MT) {
  __shared__ short bl[64 * 64];
  __shared__ short wl[128 * 64];
  const int tid = threadIdx.x;
  const int wid = tid >> 6;
  const int lane = tid & 63;
  const int ml = lane & 15;
  const int g = lane >> 4;
  const int klane = g * 8;
  const int j0 = blockIdx.x * 64;
  const int d0 = blockIdx.y * 128;

  float4_t acc[4][2];
#pragma unroll
  for (int a = 0; a < 4; ++a)
#pragma unroll
    for (int b = 0; b < 2; ++b) acc[a][b] = (float4_t)(0.0f);

  const int sr = tid >> 3;
  const int sc = (tid & 7) << 3;

  for (int kc = 0; kc < 1024; kc += 64) {
#pragma unroll
    for (int rr = sr; rr < 64; rr += 32) {
      const float* s = binding + (size_t)(j0 + rr) * 1024 + kc + sc;
      float4 f0 = *(const float4*)s;
      float4 f1 = *(const float4*)(s + 4);
      *(short8_t*)((char*)bl + ((((rr * 64 + sc) * 2) ^ ((rr & 7) << 4)))) =
          pack8(f0, f1);
    }
#pragma unroll
    for (int rr = sr; rr < 128; rr += 32) {
      const float* s = Wq + (size_t)(d0 + rr) * 1024 + kc + sc;
      float4 f0 = *(const float4*)s;
      float4 f1 = *(const float4*)(s + 4);
      *(short8_t*)((char*)wl + ((((rr * 64 + sc) * 2) ^ ((rr & 7) << 4)))) =
          pack8(f0, f1);
    }
    __syncthreads();
#pragma unroll
    for (int ks = 0; ks < 2; ++ks) {
      const int col = ks * 32 + klane;
      short8_t af[4], bfr[2];
#pragma unroll
      for (int mr = 0; mr < 4; ++mr) {
        int row = mr * 16 + ml;
        af[mr] = *(const short8_t*)((const char*)bl +
                                    (((row * 64 + col) * 2) ^ ((row & 7) << 4)));
      }
#pragma unroll
      for (int nr = 0; nr < 2; ++nr) {
        int row = wid * 32 + nr * 16 + ml;
        bfr[nr] = *(const short8_t*)((const char*)wl +
                                     (((row * 64 + col) * 2) ^ ((row & 7) << 4)));
      }
#pragma unroll
      for (int mr = 0; mr < 4; ++mr)
#pragma unroll
        for (int nr = 0; nr < 2; ++nr)
          acc[mr][nr] = MFMA16(af[mr], bfr[nr], acc[mr][nr]);
    }
    __syncthreads();
  }
#pragma unroll
  for (int mr = 0; mr < 4; ++mr)
#pragma unroll
    for (int nr = 0; nr < 2; ++nr)
#pragma unroll
      for (int i = 0; i < 4; ++i) {
        int j = j0 + mr * 16 + g * 4 + i;
        int d = d0 + wid * 32 + nr * 16 + ml;
        MT[(size_t)j * 1024 + d] = (short)f2b(acc[mr][nr][i] * 0.03125f);
      }
}

// ---------------------------------------------------------------------------
// Kernel 2: symT[k][j] = bf16(symbols[j][k])  (transpose 512x1024 -> 1024x512)
// ---------------------------------------------------------------------------
__global__ __launch_bounds__(256) void tr_kernel(const float* __restrict__ sym,
                                                 short* __restrict__ symT) {
  __shared__ short t[64][65];
  const int tid = threadIdx.x;
  const int k0 = blockIdx.x * 64;
  const int j0 = blockIdx.y * 64;
  const int sr = tid >> 3;
  const int sc = (tid & 7) << 3;
#pragma unroll
  for (int rr = sr; rr < 64; rr += 32) {
    const float* s = sym + (size_t)(j0 + rr) * 1024 + k0 + sc;
    float4 f0 = *(const float4*)s;
    float4 f1 = *(const float4*)(s + 4);
    t[rr][sc + 0] = (short)f2b(f0.x); t[rr][sc + 1] = (short)f2b(f0.y);
    t[rr][sc + 2] = (short)f2b(f0.z); t[rr][sc + 3] = (short)f2b(f0.w);
    t[rr][sc + 4] = (short)f2b(f1.x); t[rr][sc + 5] = (short)f2b(f1.y);
    t[rr][sc + 6] = (short)f2b(f1.z); t[rr][sc + 7] = (short)f2b(f1.w);
  }
  __syncthreads();
  const int kk = tid >> 4;
  const int jj = (tid & 15) << 2;
#pragma unroll
  for (int k = kk; k < 64; k += 16) {
    short* dst = symT + (size_t)(k0 + k) * 512 + j0 + jj;
    dst[0] = t[jj + 0][k];
    dst[1] = t[jj + 1][k];
    dst[2] = t[jj + 2][k];
    dst[3] = t[jj + 3][k];
  }
}

// ---------------------------------------------------------------------------
// Kernel 3: score. logitsT = MT @ bf16(inp)^T (swapped operands), row max,
// P = bf16(exp(x - m)) UNNORMALIZED -> global ws, rowinv = 1/rowsum (fp32).
// grid 512 (64-row tiles), block 512 (8 waves), wave owns a 64-j strip.
// BARRIER-FREE K-loop: no LDS staging at all. Each lane loads its MFMA
// B-fragment (8 consecutive fp32 of one inp row) directly from global —
// lanes (ml,g) tile 16 rows x 128B fully coalesced — and converts in-reg
// via v_cvt_pk_bf16_f32 (RNE, bit-identical to f2b). The 8x cross-wave
// re-read of the 64-row tile hits L2. MT fragments direct from L2 (1 MB).
// Latency hidden by wave TLP + unroll-2 ILP; no convoy, no waitcnt fences.
// ---------------------------------------------------------------------------
__global__ __launch_bounds__(512) void score_kernel(
    const float* __restrict__ inp, const short* __restrict__ MT,
    short* __restrict__ P, float* __restrict__ rowinv) {
  __shared__ float redmax[8 * 64];
  __shared__ float redsum[8 * 64];

  const int tid = threadIdx.x;
  const int wid = tid >> 6;
  const int lane = tid & 63;
  const int ml = lane & 15;
  const int g = lane >> 4;
  const size_t row0 = (size_t)blockIdx.x * 64;

  float4_t acc[4][4];  // acc[jm][rm]: D[j][r], j = wid*64+jm*16+g*4+i, r = rm*16+ml
#pragma unroll
  for (int a = 0; a < 4; ++a)
#pragma unroll
    for (int b = 0; b < 4; ++b) acc[a][b] = (float4_t)(0.0f);

  // B-fragment base: row = rm*16 + ml, k = kc*32 + g*8 (8 consecutive fp32)
  const float* inpbase = inp + (row0 + ml) * 1024 + g * 8;
  // A-fragment base: row = wid*64 + jm*16 + ml, same k
  const short* mtbase = MT + (size_t)(wid * 64 + ml) * 1024 + g * 8;

#pragma unroll 2
  for (int kc = 0; kc < 32; ++kc) {  // 32 chunks of K=32, ascending (bit-exact)
    const int off = kc * 32;
    short8_t bfr[4];
#pragma unroll
    for (int rm = 0; rm < 4; ++rm) {
      const float* s = inpbase + (size_t)rm * 16 * 1024 + off;
      float4 f0 = *(const float4*)s;
      float4 f1 = *(const float4*)(s + 4);
      uint4 u;
      u.x = cvtpk(f0.x, f0.y);
      u.y = cvtpk(f0.z, f0.w);
      u.z = cvtpk(f1.x, f1.y);
      u.w = cvtpk(f1.z, f1.w);
      bfr[rm] = __builtin_bit_cast(short8_t, u);
    }
    short8_t af[4];
#pragma unroll
    for (int jm = 0; jm < 4; ++jm)
      af[jm] = *(const short8_t*)(mtbase + (size_t)jm * 16 * 1024 + off);
#pragma unroll
    for (int jm = 0; jm < 4; ++jm)
#pragma unroll
      for (int rm = 0; rm < 4; ++rm)
        acc[jm][rm] = MFMA16(af[jm], bfr[rm], acc[jm][rm]);
  }

  // ---- row max over j (512), rows r = rm*16+ml ----
#pragma unroll
  for (int rm = 0; rm < 4; ++rm) {
    float mx = -1e30f;
#pragma unroll
    for (int jm = 0; jm < 4; ++jm)
#pragma unroll
      for (int i = 0; i < 4; ++i) mx = fmaxf(mx, acc[jm][rm][i]);
    mx = fmaxf(mx, __shfl_xor(mx, 16));
    mx = fmaxf(mx, __shfl_xor(mx, 32));
    if (g == 0) redmax[wid * 64 + rm * 16 + ml] = mx;
  }
  __syncthreads();

  // ---- exp(x-m), write unnormalized bf16 P, reduce row sums ----
#pragma unroll
  for (int rm = 0; rm < 4; ++rm) {
    const int row = rm * 16 + ml;
    float m = redmax[row];
#pragma unroll
    for (int w = 1; w < 8; ++w) m = fmaxf(m, redmax[w * 64 + row]);
    float s = 0.0f;
#pragma unroll
    for (int jm = 0; jm < 4; ++jm) {
      short4_t pv;
#pragma unroll
      for (int i = 0; i < 4; ++i) {
        float p = __expf(acc[jm][rm][i] - m);
        s += p;
        pv[i] = (short)f2b(p);
      }
      *(short4_t*)(P + ((row0 + row) << 9) + wid * 64 + jm * 16 + g * 4) = pv;
    }
    s += __shfl_xor(s, 16);
    s += __shfl_xor(s, 32);
    if (g == 0) redsum[wid * 64 + row] = s;
  }
  __syncthreads();

  // ---- wave 0 writes 1/rowsum ----
  if (wid == 0 && g == 0) {
#pragma unroll
    for (int rm = 0; rm < 4; ++rm) {
      const int row = rm * 16 + ml;
      float t = 0.0f;
#pragma unroll
      for (int w = 0; w < 8; ++w) t += redsum[w * 64 + row];
      rowinv[row0 + row] = 1.0f / t;
    }
  }
}

// ---------------------------------------------------------------------------
// Kernel 4: out[r][d] = rowinv[r] * sum_j P[r][j] * symT[d][j].  128x128 tile,
// BK=64, 256 threads (4 waves, 2x2), global_load_lds double-buffered prefetch.
// (R5-proven version, verbatim: inverse-permuted global source swizzle +
// swizzled ds_reads, vmcnt(0)+barrier+sched_barrier(0) per tile.)
// ---------------------------------------------------------------------------
__global__ __launch_bounds__(256, 2) void pv_kernel(
    const short* __restrict__ P, const short* __restrict__ symT,
    const float* __restrict__ rowinv, float* __restrict__ out) {
  __shared__ short Abuf[2][128 * 64];
  __shared__ short Bbuf[2][128 * 64];
  const int tid = threadIdx.x;
  const int lane = tid & 63;
  const int ml = lane & 15;
  const int g = lane >> 4;
  const int wid = tid >> 6;
  const int wr = wid >> 1;
  const int wc = wid & 1;

  const int b = blockIdx.x;
  const int swz = (b & 7) * 256 + (b >> 3);
  const size_t m0 = (size_t)(swz >> 3) * 128;
  const int n0 = (swz & 7) * 128;

  float4_t acc[4][4];
#pragma unroll
  for (int a = 0; a < 4; ++a)
#pragma unroll
    for (int c = 0; c < 4; ++c) acc[a][c] = (float4_t)(0.0f);

  // source col-chunk permutation: chunk ^ (row & 7)
#define STAGE(t, buf)                                                        \
  {                                                                          \
    const int kc_ = (t) * 64;                                                \
    _Pragma("unroll")                                                        \
    for (int i_ = 0; i_ < 4; ++i_) {                                         \
      const int c_ = tid + i_ * 256;                                         \
      const int r_ = c_ >> 3;                                                \
      const int ck_ = ((c_ & 7) ^ (r_ & 7)) << 3;                            \
      GLOAD_LDS16(P + (m0 + r_) * 512 + kc_ + ck_,                           \
                  (char*)Abuf[buf] + c_ * 16);                               \
    }                                                                        \
    _Pragma("unroll")                                                        \
    for (int i_ = 0; i_ < 4; ++i_) {                                         \
      const int c_ = tid + i_ * 256;                                         \
      const int r_ = c_ >> 3;                                                \
      const int ck_ = ((c_ & 7) ^ (r_ & 7)) << 3;                            \
      GLOAD_LDS16(symT + (size_t)(n0 + r_) * 512 + kc_ + ck_,                \
                  (char*)Bbuf[buf] + c_ * 16);                               \
    }                                                                        \
  }

  STAGE(0, 0);
  asm volatile("s_waitcnt vmcnt(0)" ::: "memory");
  __builtin_amdgcn_s_barrier();
  __builtin_amdgcn_sched_barrier(0);

  for (int t = 0; t < 8; ++t) {
    if (t < 7) STAGE(t + 1, (t + 1) & 1);
    const char* ab = (const char*)Abuf[t & 1];
    const char* bbp = (const char*)Bbuf[t & 1];
#pragma unroll
    for (int ks = 0; ks < 2; ++ks) {
      const int col = ks * 32 + g * 8;
      short8_t af[4], bfr[4];
#pragma unroll
      for (int mr = 0; mr < 4; ++mr) {
        const int row = wr * 64 + mr * 16 + ml;
        af[mr] = *(const short8_t*)(ab + (((row * 64 + col) * 2) ^ ((row & 7) << 4)));
      }
#pragma unroll
      for (int nr = 0; nr < 4; ++nr) {
        const int row = wc * 64 + nr * 16 + ml;
        bfr[nr] = *(const short8_t*)(bbp + (((row * 64 + col) * 2) ^ ((row & 7) << 4)));
      }
#pragma unroll
      for (int mr = 0; mr < 4; ++mr)
#pragma unroll
        for (int nr = 0; nr < 4; ++nr)
          acc[mr][nr] = MFMA16(af[mr], bfr[nr], acc[mr][nr]);
    }
    asm volatile("s_waitcnt vmcnt(0)" ::: "memory");
    __builtin_amdgcn_s_barrier();
    __builtin_amdgcn_sched_barrier(0);
  }
#undef STAGE

#pragma unroll
  for (int mr = 0; mr < 4; ++mr)
#pragma unroll
    for (int i = 0; i < 4; ++i) {
      const size_t r = m0 + wr * 64 + mr * 16 + g * 4 + i;
      const float inv = rowinv[r];
#pragma unroll
      for (int nr = 0; nr < 4; ++nr)
        out[r * 1024 + n0 + wc * 64 + nr * 16 + ml] = acc[mr][nr][i] * inv;
    }
}

extern "C" void kernel_launch(void* const* d_in, const int* in_sizes, int n_in,
                              void* d_out, int out_size, void* d_ws,
                              size_t ws_size, hipStream_t stream) {
  const float* inp = (const float*)d_in[0];      // [8,4096,1024]
  const float* Wq = (const float*)d_in[1];       // [1024,1024]
  const float* binding = (const float*)d_in[2];  // [512,1024]
  const float* symbols = (const float*)d_in[3];  // [512,1024]
  float* out = (float*)d_out;                    // [8,4096,1024]

  short* MT = (short*)d_ws;            // [512][1024] bf16 (1/32 scale folded)
  short* symT = MT + 512 * 1024;       // [1024][512] bf16
  short* P = symT + 1024 * 512;        // [32768][512] bf16 unnormalized exp
  float* rowinv = (float*)(P + (size_t)32768 * 512);  // [32768] fp32

  mt_kernel<<<dim3(8, 8), 256, 0, stream>>>(Wq, binding, MT);
  tr_kernel<<<dim3(16, 8), 256, 0, stream>>>(symbols, symT);
  score_kernel<<<512, 512, 0, stream>>>(inp, MT, P, rowinv);
  pv_kernel<<<2048, 256, 0, stream>>>(P, symT, rowinv, out);
}

// Round 9
// 250.577 us; speedup vs baseline: 1.1438x; 1.1438x over previous
//
#include <hip/hip_runtime.h>

typedef __attribute__((ext_vector_type(8))) short short8_t;
typedef __attribute__((ext_vector_type(4))) short short4_t;
typedef __attribute__((ext_vector_type(4))) float float4_t;

#define MFMA16(a, b, c) __builtin_amdgcn_mfma_f32_16x16x32_bf16((a), (b), (c), 0, 0, 0)
#define GLOAD_LDS16(g, l)                                                   \
  __builtin_amdgcn_global_load_lds(                                         \
      (const __attribute__((address_space(1))) void*)(g),                   \
      (__attribute__((address_space(3))) void*)(l), 16, 0, 0)

// fp32 -> bf16 round-to-nearest-even (finite inputs only)
static __device__ __forceinline__ unsigned short f2b(float f) {
  unsigned int x = __builtin_bit_cast(unsigned int, f);
  x = (x + 0x7fffu + ((x >> 16) & 1u)) >> 16;
  return (unsigned short)x;
}

static __device__ __forceinline__ short8_t pack8(float4 x, float4 y) {
  short8_t v;
  v[0] = (short)f2b(x.x); v[1] = (short)f2b(x.y);
  v[2] = (short)f2b(x.z); v[3] = (short)f2b(x.w);
  v[4] = (short)f2b(y.x); v[5] = (short)f2b(y.y);
  v[6] = (short)f2b(y.z); v[7] = (short)f2b(y.w);
  return v;
}

// ---------------------------------------------------------------------------
// Kernel 1: MT[j][d] = (1/32) * sum_k binding[j][k] * Wq[d][k]   (bf16 out)
// ---------------------------------------------------------------------------
__global__ __launch_bounds__(256, 2) void mt_kernel(
    const float* __restrict__ Wq, const float* __restrict__ binding,
    short* __restrict__ MT) {
  __shared__ short bl[64 * 64];
  __shared__ short wl[128 * 64];
  const int tid = threadIdx.x;
  const int wid = tid >> 6;
  const int lane = tid & 63;
  const int ml = lane & 15;
  const int g = lane >> 4;
  const int klane = g * 8;
  const int j0 = blockIdx.x * 64;
  const int d0 = blockIdx.y * 128;

  float4_t acc[4][2];
#pragma unroll
  for (int a = 0; a < 4; ++a)
#pragma unroll
    for (int b = 0; b < 2; ++b) acc[a][b] = (float4_t)(0.0f);

  const int sr = tid >> 3;
  const int sc = (tid & 7) << 3;

  for (int kc = 0; kc < 1024; kc += 64) {
#pragma unroll
    for (int rr = sr; rr < 64; rr += 32) {
      const float* s = binding + (size_t)(j0 + rr) * 1024 + kc + sc;
      float4 f0 = *(const float4*)s;
      float4 f1 = *(const float4*)(s + 4);
      *(short8_t*)((char*)bl + ((((rr * 64 + sc) * 2) ^ ((rr & 7) << 4)))) =
          pack8(f0, f1);
    }
#pragma unroll
    for (int rr = sr; rr < 128; rr += 32) {
      const float* s = Wq + (size_t)(d0 + rr) * 1024 + kc + sc;
      float4 f0 = *(const float4*)s;
      float4 f1 = *(const float4*)(s + 4);
      *(short8_t*)((char*)wl + ((((rr * 64 + sc) * 2) ^ ((rr & 7) << 4)))) =
          pack8(f0, f1);
    }
    __syncthreads();
#pragma unroll
    for (int ks = 0; ks < 2; ++ks) {
      const int col = ks * 32 + klane;
      short8_t af[4], bfr[2];
#pragma unroll
      for (int mr = 0; mr < 4; ++mr) {
        int row = mr * 16 + ml;
        af[mr] = *(const short8_t*)((const char*)bl +
                                    (((row * 64 + col) * 2) ^ ((row & 7) << 4)));
      }
#pragma unroll
      for (int nr = 0; nr < 2; ++nr) {
        int row = wid * 32 + nr * 16 + ml;
        bfr[nr] = *(const short8_t*)((const char*)wl +
                                     (((row * 64 + col) * 2) ^ ((row & 7) << 4)));
      }
#pragma unroll
      for (int mr = 0; mr < 4; ++mr)
#pragma unroll
        for (int nr = 0; nr < 2; ++nr)
          acc[mr][nr] = MFMA16(af[mr], bfr[nr], acc[mr][nr]);
    }
    __syncthreads();
  }
#pragma unroll
  for (int mr = 0; mr < 4; ++mr)
#pragma unroll
    for (int nr = 0; nr < 2; ++nr)
#pragma unroll
      for (int i = 0; i < 4; ++i) {
        int j = j0 + mr * 16 + g * 4 + i;
        int d = d0 + wid * 32 + nr * 16 + ml;
        MT[(size_t)j * 1024 + d] = (short)f2b(acc[mr][nr][i] * 0.03125f);
      }
}

// ---------------------------------------------------------------------------
// Kernel 2: symT[k][j] = bf16(symbols[j][k])  (transpose 512x1024 -> 1024x512)
// ---------------------------------------------------------------------------
__global__ __launch_bounds__(256) void tr_kernel(const float* __restrict__ sym,
                                                 short* __restrict__ symT) {
  __shared__ short t[64][65];
  const int tid = threadIdx.x;
  const int k0 = blockIdx.x * 64;
  const int j0 = blockIdx.y * 64;
  const int sr = tid >> 3;
  const int sc = (tid & 7) << 3;
#pragma unroll
  for (int rr = sr; rr < 64; rr += 32) {
    const float* s = sym + (size_t)(j0 + rr) * 1024 + k0 + sc;
    float4 f0 = *(const float4*)s;
    float4 f1 = *(const float4*)(s + 4);
    t[rr][sc + 0] = (short)f2b(f0.x); t[rr][sc + 1] = (short)f2b(f0.y);
    t[rr][sc + 2] = (short)f2b(f0.z); t[rr][sc + 3] = (short)f2b(f0.w);
    t[rr][sc + 4] = (short)f2b(f1.x); t[rr][sc + 5] = (short)f2b(f1.y);
    t[rr][sc + 6] = (short)f2b(f1.z); t[rr][sc + 7] = (short)f2b(f1.w);
  }
  __syncthreads();
  const int kk = tid >> 4;
  const int jj = (tid & 15) << 2;
#pragma unroll
  for (int k = kk; k < 64; k += 16) {
    short* dst = symT + (size_t)(k0 + k) * 512 + j0 + jj;
    dst[0] = t[jj + 0][k];
    dst[1] = t[jj + 1][k];
    dst[2] = t[jj + 2][k];
    dst[3] = t[jj + 3][k];
  }
}

// ---------------------------------------------------------------------------
// Kernel 3: score. logitsT = MT @ bf16(inp)^T (swapped operands), row max,
// P = bf16(exp(x - m)) UNNORMALIZED -> global ws, rowinv = 1/rowsum (fp32).
// SMALL SYNC DOMAINS: grid 1024 x 32-row tiles, 256 threads (4 waves), wave
// owns a 128-j strip. ~3 blocks/CU -> independent barrier convoys interleave
// (R5's 8-wave/1-block convoy was fully exposed: occupancy 21%, all pipes
// <15%). R5-proven sync skeleton per kt: stage write -> MT loads -> inp
// prefetch -> lgkmcnt(0) -> s_barrier -> sched_barrier(0) -> ds_reads+MFMA.
// jm split into 2 halves of 4 to cap af register pressure.
// ---------------------------------------------------------------------------
__global__ __launch_bounds__(256) void score_kernel(
    const float* __restrict__ inp, const short* __restrict__ MT,
    short* __restrict__ P, float* __restrict__ rowinv) {
  __shared__ short Abuf[2][32 * 64];
  __shared__ float redmax[4 * 32];
  __shared__ float redsum[4 * 32];

  const int tid = threadIdx.x;
  const int wid = tid >> 6;   // 0..3
  const int lane = tid & 63;
  const int ml = lane & 15;
  const int g = lane >> 4;
  const size_t row0 = (size_t)blockIdx.x * 32;

  float4_t acc[8][2];  // acc[jm][rm]: D[j][r], j = wid*128+jm*16+g*4+i, r = rm*16+ml
#pragma unroll
  for (int a = 0; a < 8; ++a)
#pragma unroll
    for (int b = 0; b < 2; ++b) acc[a][b] = (float4_t)(0.0f);

  const int sr = tid >> 3;        // 0..31 row within tile (1 chunk per thread)
  const int sc = (tid & 7) << 3;  // col chunk
  const float* srcbase = inp + (row0 + sr) * 1024 + sc;
  const short* mtbase = MT + (size_t)(wid * 128 + ml) * 1024 + g * 8;
  const int lds_off = ((sr * 64 + sc) * 2) ^ ((sr & 7) << 4);

  float4 f0 = *(const float4*)(srcbase);
  float4 f1 = *(const float4*)(srcbase + 4);

  for (int kt = 0; kt < 16; ++kt) {
    // stage tile kt (prefetched fp32 -> bf16, swizzled LDS write)
    *(short8_t*)((char*)Abuf[kt & 1] + lds_off) = pack8(f0, f1);
    // prefetch tile kt+1 (global loads stay in flight across the barrier)
    if (kt < 15) {
      const float* s2 = srcbase + (kt + 1) * 64;
      f0 = *(const float4*)s2;
      f1 = *(const float4*)(s2 + 4);
    }
    // drain own LDS write only; global loads remain outstanding
    asm volatile("s_waitcnt lgkmcnt(0)" ::: "memory");
    __builtin_amdgcn_s_barrier();
    // rule-18 fence: ds_reads below must not hoist above the barrier
    __builtin_amdgcn_sched_barrier(0);

    const char* bb = (const char*)Abuf[kt & 1];
    const short* mtb = mtbase + kt * 64;
    // B fragments (both ks) once per kt
    short8_t bfr[2][2];
#pragma unroll
    for (int ks = 0; ks < 2; ++ks) {
      const int col = ks * 32 + g * 8;
#pragma unroll
      for (int rm = 0; rm < 2; ++rm) {
        int row = rm * 16 + ml;
        bfr[ks][rm] =
            *(const short8_t*)(bb + (((row * 64 + col) * 2) ^ ((row & 7) << 4)));
      }
    }
    // jm in 2 halves of 4: second half's MT loads overlap first half's MFMAs
#pragma unroll
    for (int jh = 0; jh < 2; ++jh) {
      short8_t af0[4], af1[4];
#pragma unroll
      for (int j4 = 0; j4 < 4; ++j4) {
        const short* m = mtb + (size_t)(jh * 4 + j4) * 16 * 1024;
        af0[j4] = *(const short8_t*)(m);
        af1[j4] = *(const short8_t*)(m + 32);
      }
#pragma unroll
      for (int j4 = 0; j4 < 4; ++j4)
#pragma unroll
        for (int rm = 0; rm < 2; ++rm) {
          acc[jh * 4 + j4][rm] = MFMA16(af0[j4], bfr[0][rm], acc[jh * 4 + j4][rm]);
          acc[jh * 4 + j4][rm] = MFMA16(af1[j4], bfr[1][rm], acc[jh * 4 + j4][rm]);
        }
    }
    // no trailing barrier: next write targets the other buffer; the kt+1
    // barrier (all waves' lgkm drained) orders reuse of this buffer.
  }

  // ---- row max over j (512), rows r = rm*16+ml ----
#pragma unroll
  for (int rm = 0; rm < 2; ++rm) {
    float mx = -1e30f;
#pragma unroll
    for (int jm = 0; jm < 8; ++jm)
#pragma unroll
      for (int i = 0; i < 4; ++i) mx = fmaxf(mx, acc[jm][rm][i]);
    mx = fmaxf(mx, __shfl_xor(mx, 16));
    mx = fmaxf(mx, __shfl_xor(mx, 32));
    if (g == 0) redmax[wid * 32 + rm * 16 + ml] = mx;
  }
  __syncthreads();

  // ---- exp(x-m), write unnormalized bf16 P, reduce row sums ----
#pragma unroll
  for (int rm = 0; rm < 2; ++rm) {
    const int row = rm * 16 + ml;
    float m = redmax[row];
#pragma unroll
    for (int w = 1; w < 4; ++w) m = fmaxf(m, redmax[w * 32 + row]);
    float s = 0.0f;
#pragma unroll
    for (int jm = 0; jm < 8; ++jm) {
      short4_t pv;
#pragma unroll
      for (int i = 0; i < 4; ++i) {
        float p = __expf(acc[jm][rm][i] - m);
        s += p;
        pv[i] = (short)f2b(p);
      }
      *(short4_t*)(P + ((row0 + row) << 9) + wid * 128 + jm * 16 + g * 4) = pv;
    }
    s += __shfl_xor(s, 16);
    s += __shfl_xor(s, 32);
    if (g == 0) redsum[wid * 32 + row] = s;
  }
  __syncthreads();

  // ---- wave 0 writes 1/rowsum ----
  if (wid == 0 && g == 0) {
#pragma unroll
    for (int rm = 0; rm < 2; ++rm) {
      const int row = rm * 16 + ml;
      float t = 0.0f;
#pragma unroll
      for (int w = 0; w < 4; ++w) t += redsum[w * 32 + row];
      rowinv[row0 + row] = 1.0f / t;
    }
  }
}

// ---------------------------------------------------------------------------
// Kernel 4: out[r][d] = rowinv[r] * sum_j P[r][j] * symT[d][j].  128x128 tile,
// BK=64, 256 threads (4 waves, 2x2), global_load_lds double-buffered prefetch.
// (R5-proven version, verbatim: inverse-permuted global source swizzle +
// swizzled ds_reads, vmcnt(0)+barrier+sched_barrier(0) per tile.)
// ---------------------------------------------------------------------------
__global__ __launch_bounds__(256, 2) void pv_kernel(
    const short* __restrict__ P, const short* __restrict__ symT,
    const float* __restrict__ rowinv, float* __restrict__ out) {
  __shared__ short Abuf[2][128 * 64];
  __shared__ short Bbuf[2][128 * 64];
  const int tid = threadIdx.x;
  const int lane = tid & 63;
  const int ml = lane & 15;
  const int g = lane >> 4;
  const int wid = tid >> 6;
  const int wr = wid >> 1;
  const int wc = wid & 1;

  const int b = blockIdx.x;
  const int swz = (b & 7) * 256 + (b >> 3);
  const size_t m0 = (size_t)(swz >> 3) * 128;
  const int n0 = (swz & 7) * 128;

  float4_t acc[4][4];
#pragma unroll
  for (int a = 0; a < 4; ++a)
#pragma unroll
    for (int c = 0; c < 4; ++c) acc[a][c] = (float4_t)(0.0f);

  // source col-chunk permutation: chunk ^ (row & 7)
#define STAGE(t, buf)                                                        \
  {                                                                          \
    const int kc_ = (t) * 64;                                                \
    _Pragma("unroll")                                                        \
    for (int i_ = 0; i_ < 4; ++i_) {                                         \
      const int c_ = tid + i_ * 256;                                         \
      const int r_ = c_ >> 3;                                                \
      const int ck_ = ((c_ & 7) ^ (r_ & 7)) << 3;                            \
      GLOAD_LDS16(P + (m0 + r_) * 512 + kc_ + ck_,                           \
                  (char*)Abuf[buf] + c_ * 16);                               \
    }                                                                        \
    _Pragma("unroll")                                                        \
    for (int i_ = 0; i_ < 4; ++i_) {                                         \
      const int c_ = tid + i_ * 256;                                         \
      const int r_ = c_ >> 3;                                                \
      const int ck_ = ((c_ & 7) ^ (r_ & 7)) << 3;                            \
      GLOAD_LDS16(symT + (size_t)(n0 + r_) * 512 + kc_ + ck_,                \
                  (char*)Bbuf[buf] + c_ * 16);                               \
    }                                                                        \
  }

  STAGE(0, 0);
  asm volatile("s_waitcnt vmcnt(0)" ::: "memory");
  __builtin_amdgcn_s_barrier();
  __builtin_amdgcn_sched_barrier(0);

  for (int t = 0; t < 8; ++t) {
    if (t < 7) STAGE(t + 1, (t + 1) & 1);
    const char* ab = (const char*)Abuf[t & 1];
    const char* bbp = (const char*)Bbuf[t & 1];
#pragma unroll
    for (int ks = 0; ks < 2; ++ks) {
      const int col = ks * 32 + g * 8;
      short8_t af[4], bfr[4];
#pragma unroll
      for (int mr = 0; mr < 4; ++mr) {
        const int row = wr * 64 + mr * 16 + ml;
        af[mr] = *(const short8_t*)(ab + (((row * 64 + col) * 2) ^ ((row & 7) << 4)));
      }
#pragma unroll
      for (int nr = 0; nr < 4; ++nr) {
        const int row = wc * 64 + nr * 16 + ml;
        bfr[nr] = *(const short8_t*)(bbp + (((row * 64 + col) * 2) ^ ((row & 7) << 4)));
      }
#pragma unroll
      for (int mr = 0; mr < 4; ++mr)
#pragma unroll
        for (int nr = 0; nr < 4; ++nr)
          acc[mr][nr] = MFMA16(af[mr], bfr[nr], acc[mr][nr]);
    }
    asm volatile("s_waitcnt vmcnt(0)" ::: "memory");
    __builtin_amdgcn_s_barrier();
    __builtin_amdgcn_sched_barrier(0);
  }
#undef STAGE

#pragma unroll
  for (int mr = 0; mr < 4; ++mr)
#pragma unroll
    for (int i = 0; i < 4; ++i) {
      const size_t r = m0 + wr * 64 + mr * 16 + g * 4 + i;
      const float inv = rowinv[r];
#pragma unroll
      for (int nr = 0; nr < 4; ++nr)
        out[r * 1024 + n0 + wc * 64 + nr * 16 + ml] = acc[mr][nr][i] * inv;
    }
}

extern "C" void kernel_launch(void* const* d_in, const int* in_sizes, int n_in,
                              void* d_out, int out_size, void* d_ws,
                              size_t ws_size, hipStream_t stream) {
  const float* inp = (const float*)d_in[0];      // [8,4096,1024]
  const float* Wq = (const float*)d_in[1];       // [1024,1024]
  const float* binding = (const float*)d_in[2];  // [512,1024]
  const float* symbols = (const float*)d_in[3];  // [512,1024]
  float* out = (float*)d_out;                    // [8,4096,1024]

  short* MT = (short*)d_ws;            // [512][1024] bf16 (1/32 scale folded)
  short* symT = MT + 512 * 1024;       // [1024][512] bf16
  short* P = symT + 1024 * 512;        // [32768][512] bf16 unnormalized exp
  float* rowinv = (float*)(P + (size_t)32768 * 512);  // [32768] fp32

  mt_kernel<<<dim3(8, 8), 256, 0, stream>>>(Wq, binding, MT);
  tr_kernel<<<dim3(16, 8), 256, 0, stream>>>(symbols, symT);
  score_kernel<<<1024, 256, 0, stream>>>(inp, MT, P, rowinv);
  pv_kernel<<<2048, 256, 0, stream>>>(P, symT, rowinv, out);
}

// Round 10
// 182.209 us; speedup vs baseline: 1.5729x; 1.3752x over previous
//
#include <hip/hip_runtime.h>

typedef __attribute__((ext_vector_type(8))) short short8_t;
typedef __attribute__((ext_vector_type(4))) short short4_t;
typedef __attribute__((ext_vector_type(4))) float float4_t;

#define MFMA16(a, b, c) __builtin_amdgcn_mfma_f32_16x16x32_bf16((a), (b), (c), 0, 0, 0)
#define GLOAD_LDS16(g, l)                                                   \
  __builtin_amdgcn_global_load_lds(                                         \
      (const __attribute__((address_space(1))) void*)(g),                   \
      (__attribute__((address_space(3))) void*)(l), 16, 0, 0)

// fp32 -> bf16 round-to-nearest-even (finite inputs only)
static __device__ __forceinline__ unsigned short f2b(float f) {
  unsigned int x = __builtin_bit_cast(unsigned int, f);
  x = (x + 0x7fffu + ((x >> 16) & 1u)) >> 16;
  return (unsigned short)x;
}

static __device__ __forceinline__ short8_t pack8(float4 x, float4 y) {
  short8_t v;
  v[0] = (short)f2b(x.x); v[1] = (short)f2b(x.y);
  v[2] = (short)f2b(x.z); v[3] = (short)f2b(x.w);
  v[4] = (short)f2b(y.x); v[5] = (short)f2b(y.y);
  v[6] = (short)f2b(y.z); v[7] = (short)f2b(y.w);
  return v;
}

// ---------------------------------------------------------------------------
// Kernel 1: MT[j][d] = (1/32) * sum_k binding[j][k] * Wq[d][k]   (bf16 out)
// ---------------------------------------------------------------------------
__global__ __launch_bounds__(256, 2) void mt_kernel(
    const float* __restrict__ Wq, const float* __restrict__ binding,
    short* __restrict__ MT) {
  __shared__ short bl[64 * 64];
  __shared__ short wl[128 * 64];
  const int tid = threadIdx.x;
  const int wid = tid >> 6;
  const int lane = tid & 63;
  const int ml = lane & 15;
  const int g = lane >> 4;
  const int klane = g * 8;
  const int j0 = blockIdx.x * 64;
  const int d0 = blockIdx.y * 128;

  float4_t acc[4][2];
#pragma unroll
  for (int a = 0; a < 4; ++a)
#pragma unroll
    for (int b = 0; b < 2; ++b) acc[a][b] = (float4_t)(0.0f);

  const int sr = tid >> 3;
  const int sc = (tid & 7) << 3;

  for (int kc = 0; kc < 1024; kc += 64) {
#pragma unroll
    for (int rr = sr; rr < 64; rr += 32) {
      const float* s = binding + (size_t)(j0 + rr) * 1024 + kc + sc;
      float4 f0 = *(const float4*)s;
      float4 f1 = *(const float4*)(s + 4);
      *(short8_t*)((char*)bl + ((((rr * 64 + sc) * 2) ^ ((rr & 7) << 4)))) =
          pack8(f0, f1);
    }
#pragma unroll
    for (int rr = sr; rr < 128; rr += 32) {
      const float* s = Wq + (size_t)(d0 + rr) * 1024 + kc + sc;
      float4 f0 = *(const float4*)s;
      float4 f1 = *(const float4*)(s + 4);
      *(short8_t*)((char*)wl + ((((rr * 64 + sc) * 2) ^ ((rr & 7) << 4)))) =
          pack8(f0, f1);
    }
    __syncthreads();
#pragma unroll
    for (int ks = 0; ks < 2; ++ks) {
      const int col = ks * 32 + klane;
      short8_t af[4], bfr[2];
#pragma unroll
      for (int mr = 0; mr < 4; ++mr) {
        int row = mr * 16 + ml;
        af[mr] = *(const short8_t*)((const char*)bl +
                                    (((row * 64 + col) * 2) ^ ((row & 7) << 4)));
      }
#pragma unroll
      for (int nr = 0; nr < 2; ++nr) {
        int row = wid * 32 + nr * 16 + ml;
        bfr[nr] = *(const short8_t*)((const char*)wl +
                                     (((row * 64 + col) * 2) ^ ((row & 7) << 4)));
      }
#pragma unroll
      for (int mr = 0; mr < 4; ++mr)
#pragma unroll
        for (int nr = 0; nr < 2; ++nr)
          acc[mr][nr] = MFMA16(af[mr], bfr[nr], acc[mr][nr]);
    }
    __syncthreads();
  }
#pragma unroll
  for (int mr = 0; mr < 4; ++mr)
#pragma unroll
    for (int nr = 0; nr < 2; ++nr)
#pragma unroll
      for (int i = 0; i < 4; ++i) {
        int j = j0 + mr * 16 + g * 4 + i;
        int d = d0 + wid * 32 + nr * 16 + ml;
        MT[(size_t)j * 1024 + d] = (short)f2b(acc[mr][nr][i] * 0.03125f);
      }
}

// ---------------------------------------------------------------------------
// Kernel 2: symT[k][j] = bf16(symbols[j][k])  (transpose 512x1024 -> 1024x512)
// ---------------------------------------------------------------------------
__global__ __launch_bounds__(256) void tr_kernel(const float* __restrict__ sym,
                                                 short* __restrict__ symT) {
  __shared__ short t[64][65];
  const int tid = threadIdx.x;
  const int k0 = blockIdx.x * 64;
  const int j0 = blockIdx.y * 64;
  const int sr = tid >> 3;
  const int sc = (tid & 7) << 3;
#pragma unroll
  for (int rr = sr; rr < 64; rr += 32) {
    const float* s = sym + (size_t)(j0 + rr) * 1024 + k0 + sc;
    float4 f0 = *(const float4*)s;
    float4 f1 = *(const float4*)(s + 4);
    t[rr][sc + 0] = (short)f2b(f0.x); t[rr][sc + 1] = (short)f2b(f0.y);
    t[rr][sc + 2] = (short)f2b(f0.z); t[rr][sc + 3] = (short)f2b(f0.w);
    t[rr][sc + 4] = (short)f2b(f1.x); t[rr][sc + 5] = (short)f2b(f1.y);
    t[rr][sc + 6] = (short)f2b(f1.z); t[rr][sc + 7] = (short)f2b(f1.w);
  }
  __syncthreads();
  const int kk = tid >> 4;
  const int jj = (tid & 15) << 2;
#pragma unroll
  for (int k = kk; k < 64; k += 16) {
    short* dst = symT + (size_t)(k0 + k) * 512 + j0 + jj;
    dst[0] = t[jj + 0][k];
    dst[1] = t[jj + 1][k];
    dst[2] = t[jj + 2][k];
    dst[3] = t[jj + 3][k];
  }
}

// ---------------------------------------------------------------------------
// Kernel 3: score (R5-EXACT, proven 89.5 us). logitsT = MT @ bf16(inp)^T,
// row max, P = bf16(exp(x-m)) unnormalized -> ws, rowinv = 1/rowsum.
// grid 512 (64-row tiles), 512 threads (8 waves), wave owns a 64-j strip.
// MT fragment loads hoisted ABOVE the barrier (R4->R5 key win, re-confirmed
// by R9's regression when moved below); sched_barrier(0) = rule-18 fence.
// ---------------------------------------------------------------------------
__global__ __launch_bounds__(512, 2) void score_kernel(
    const float* __restrict__ inp, const short* __restrict__ MT,
    short* __restrict__ P, float* __restrict__ rowinv) {
  __shared__ short Abuf[2][64 * 64];
  __shared__ float redmax[8 * 64];
  __shared__ float redsum[8 * 64];

  const int tid = threadIdx.x;
  const int wid = tid >> 6;
  const int lane = tid & 63;
  const int ml = lane & 15;
  const int g = lane >> 4;
  const size_t row0 = (size_t)blockIdx.x * 64;

  float4_t acc[4][4];  // acc[jm][rm]: D[j][r], j = wid*64+jm*16+g*4+i, r = rm*16+ml
#pragma unroll
  for (int a = 0; a < 4; ++a)
#pragma unroll
    for (int b = 0; b < 4; ++b) acc[a][b] = (float4_t)(0.0f);

  const int sr = tid >> 3;        // 0..63 row within tile
  const int sc = (tid & 7) << 3;  // col chunk
  const float* srcbase = inp + (row0 + sr) * 1024 + sc;
  const short* mtbase = MT + (size_t)(wid * 64 + ml) * 1024 + g * 8;
  const int lds_off = ((sr * 64 + sc) * 2) ^ ((sr & 7) << 4);

  float4 f0 = *(const float4*)(srcbase);
  float4 f1 = *(const float4*)(srcbase + 4);

  for (int kt = 0; kt < 16; ++kt) {
    // convert prefetched fp32 -> bf16, write to current LDS buffer (swizzled)
    *(short8_t*)((char*)Abuf[kt & 1] + lds_off) = pack8(f0, f1);

    // current kt's MT fragments — global loads, issued BEFORE the barrier so
    // L2 latency overlaps the barrier + ds_reads.
    const short* mtb = mtbase + kt * 64;
    short8_t af0[4], af1[4];
#pragma unroll
    for (int jm = 0; jm < 4; ++jm) {
      af0[jm] = *(const short8_t*)(mtb + jm * 16 * 1024);
      af1[jm] = *(const short8_t*)(mtb + jm * 16 * 1024 + 32);
    }

    // issue next tile's inp loads (consumed at next iteration's convert)
    if (kt < 15) {
      const float* s2 = srcbase + (kt + 1) * 64;
      f0 = *(const float4*)s2;
      f1 = *(const float4*)(s2 + 4);
    }

    // drain own LDS write; global loads stay in flight
    asm volatile("s_waitcnt lgkmcnt(0)" ::: "memory");
    __builtin_amdgcn_s_barrier();
    // pin: the Abuf ds_reads below may not hoist above the barrier
    __builtin_amdgcn_sched_barrier(0);

    const char* bb = (const char*)Abuf[kt & 1];
#pragma unroll
    for (int ks = 0; ks < 2; ++ks) {
      const int col = ks * 32 + g * 8;
      short8_t bfr[4];
#pragma unroll
      for (int rm = 0; rm < 4; ++rm) {
        int row = rm * 16 + ml;
        bfr[rm] = *(const short8_t*)(bb + (((row * 64 + col) * 2) ^ ((row & 7) << 4)));
      }
#pragma unroll
      for (int jm = 0; jm < 4; ++jm)
#pragma unroll
        for (int rm = 0; rm < 4; ++rm)
          acc[jm][rm] = MFMA16(ks == 0 ? af0[jm] : af1[jm], bfr[rm], acc[jm][rm]);
    }
    // no trailing barrier: next write targets the other buffer; the kt+1
    // barrier (all waves' lgkm drained) orders reuse of this buffer.
  }

  // ---- row max over j (512), rows r = rm*16+ml ----
#pragma unroll
  for (int rm = 0; rm < 4; ++rm) {
    float mx = -1e30f;
#pragma unroll
    for (int jm = 0; jm < 4; ++jm)
#pragma unroll
      for (int i = 0; i < 4; ++i) mx = fmaxf(mx, acc[jm][rm][i]);
    mx = fmaxf(mx, __shfl_xor(mx, 16));
    mx = fmaxf(mx, __shfl_xor(mx, 32));
    if (g == 0) redmax[wid * 64 + rm * 16 + ml] = mx;
  }
  __syncthreads();

  // ---- exp(x-m), write unnormalized bf16 P, reduce row sums ----
#pragma unroll
  for (int rm = 0; rm < 4; ++rm) {
    const int row = rm * 16 + ml;
    float m = redmax[row];
#pragma unroll
    for (int w = 1; w < 8; ++w) m = fmaxf(m, redmax[w * 64 + row]);
    float s = 0.0f;
#pragma unroll
    for (int jm = 0; jm < 4; ++jm) {
      short4_t pv;
#pragma unroll
      for (int i = 0; i < 4; ++i) {
        float p = __expf(acc[jm][rm][i] - m);
        s += p;
        pv[i] = (short)f2b(p);
      }
      *(short4_t*)(P + ((row0 + row) << 9) + wid * 64 + jm * 16 + g * 4) = pv;
    }
    s += __shfl_xor(s, 16);
    s += __shfl_xor(s, 32);
    if (g == 0) redsum[wid * 64 + row] = s;
  }
  __syncthreads();

  // ---- wave 0 writes 1/rowsum ----
  if (wid == 0 && g == 0) {
#pragma unroll
    for (int rm = 0; rm < 4; ++rm) {
      const int row = rm * 16 + ml;
      float t = 0.0f;
#pragma unroll
      for (int w = 0; w < 8; ++w) t += redsum[w * 64 + row];
      rowinv[row0 + row] = 1.0f / t;
    }
  }
}

// ---------------------------------------------------------------------------
// Kernel 4: out[r][d] = rowinv[r] * sum_j P[r][j] * symT[d][j].  128x128 tile,
// BK=32, 16 K-tiles, 256 threads (4 waves, 2x2).  TRIPLE-BUFFER + COUNTED
// vmcnt (T4): per iter {vmcnt(4) [drain oldest tile only] -> barrier ->
// sched_barrier(0) -> STAGE(t+2) -> compute(t)}.  Loads for t+1/t+2 stay in
// flight across the barrier; tile t's loads were issued 2 iters ago (~2
// compute spans of slack).  Race-safety: STAGE(t+2) (writes buf[(t+2)%3], the
// buffer compute(t-1) read) is pinned below the barrier by sched_barrier(0),
// and all waves passed that barrier only after finishing compute(t-1).
// Swizzle: source chunk ^= (row>>1)&3 (involution, both sides), uniform banks.
// K-order: tiles ascending x g-chunk -> accumulation order bit-identical R5.
// ---------------------------------------------------------------------------
__global__ __launch_bounds__(256, 2) void pv_kernel(
    const short* __restrict__ P, const short* __restrict__ symT,
    const float* __restrict__ rowinv, float* __restrict__ out) {
  __shared__ short Abuf[3][128 * 32];
  __shared__ short Bbuf[3][128 * 32];
  const int tid = threadIdx.x;
  const int lane = tid & 63;
  const int ml = lane & 15;
  const int g = lane >> 4;
  const int wid = tid >> 6;
  const int wr = wid >> 1;
  const int wc = wid & 1;

  const int b = blockIdx.x;
  const int swz = (b & 7) * 256 + (b >> 3);
  const size_t m0 = (size_t)(swz >> 3) * 128;
  const int n0 = (swz & 7) * 128;

  float4_t acc[4][4];
#pragma unroll
  for (int a = 0; a < 4; ++a)
#pragma unroll
    for (int c = 0; c < 4; ++c) acc[a][c] = (float4_t)(0.0f);

  // 4 gload_lds per thread per STAGE (2 A + 2 B); 512 chunks of 16B per
  // operand per tile; row = chunk>>2, chunk-in-row permuted by (row>>1)&3.
#define STAGE(t, buf)                                                        \
  {                                                                          \
    _Pragma("unroll")                                                        \
    for (int i_ = 0; i_ < 2; ++i_) {                                         \
      const int c_ = tid + i_ * 256;                                         \
      const int r_ = c_ >> 2;                                                \
      const int ck_ = ((c_ & 3) ^ ((r_ >> 1) & 3)) << 3;                     \
      GLOAD_LDS16(P + (m0 + r_) * 512 + (t) * 32 + ck_,                      \
                  (char*)Abuf[buf] + c_ * 16);                               \
      GLOAD_LDS16(symT + (size_t)(n0 + r_) * 512 + (t) * 32 + ck_,           \
                  (char*)Bbuf[buf] + c_ * 16);                               \
    }                                                                        \
  }

#define COMPUTE(bufidx)                                                      \
  {                                                                          \
    const char* ab_ = (const char*)Abuf[bufidx];                             \
    const char* bb_ = (const char*)Bbuf[bufidx];                             \
    short8_t af[4], bfr[4];                                                  \
    _Pragma("unroll")                                                        \
    for (int mr = 0; mr < 4; ++mr) {                                         \
      const int row = wr * 64 + mr * 16 + ml;                                \
      af[mr] = *(const short8_t*)(ab_ + row * 64 +                           \
                                  ((g ^ ((row >> 1) & 3)) << 4));            \
    }                                                                        \
    _Pragma("unroll")                                                        \
    for (int nr = 0; nr < 4; ++nr) {                                         \
      const int row = wc * 64 + nr * 16 + ml;                                \
      bfr[nr] = *(const short8_t*)(bb_ + row * 64 +                          \
                                   ((g ^ ((row >> 1) & 3)) << 4));           \
    }                                                                        \
    _Pragma("unroll")                                                        \
    for (int mr = 0; mr < 4; ++mr)                                           \
      _Pragma("unroll")                                                      \
      for (int nr = 0; nr < 4; ++nr)                                         \
        acc[mr][nr] = MFMA16(af[mr], bfr[nr], acc[mr][nr]);                  \
  }

  STAGE(0, 0);
  STAGE(1, 1);
  // invariant at top of iter t: tiles t and t+1 outstanding (4 loads each)
#pragma unroll
  for (int t = 0; t < 15; ++t) {
    asm volatile("s_waitcnt vmcnt(4)" ::: "memory");  // oldest tile landed
    __builtin_amdgcn_s_barrier();
    __builtin_amdgcn_sched_barrier(0);  // STAGE+ds_reads may not hoist above
    if (t < 14) STAGE(t + 2, (t + 2) % 3);
    COMPUTE(t % 3);
  }
  asm volatile("s_waitcnt vmcnt(0)" ::: "memory");
  __builtin_amdgcn_s_barrier();
  __builtin_amdgcn_sched_barrier(0);
  COMPUTE(0);  // t = 15, 15 % 3 = 0
#undef STAGE
#undef COMPUTE

#pragma unroll
  for (int mr = 0; mr < 4; ++mr)
#pragma unroll
    for (int i = 0; i < 4; ++i) {
      const size_t r = m0 + wr * 64 + mr * 16 + g * 4 + i;
      const float inv = rowinv[r];
#pragma unroll
      for (int nr = 0; nr < 4; ++nr)
        out[r * 1024 + n0 + wc * 64 + nr * 16 + ml] = acc[mr][nr][i] * inv;
    }
}

extern "C" void kernel_launch(void* const* d_in, const int* in_sizes, int n_in,
                              void* d_out, int out_size, void* d_ws,
                              size_t ws_size, hipStream_t stream) {
  const float* inp = (const float*)d_in[0];      // [8,4096,1024]
  const float* Wq = (const float*)d_in[1];       // [1024,1024]
  const float* binding = (const float*)d_in[2];  // [512,1024]
  const float* symbols = (const float*)d_in[3];  // [512,1024]
  float* out = (float*)d_out;                    // [8,4096,1024]

  short* MT = (short*)d_ws;            // [512][1024] bf16 (1/32 scale folded)
  short* symT = MT + 512 * 1024;       // [1024][512] bf16
  short* P = symT + 1024 * 512;        // [32768][512] bf16 unnormalized exp
  float* rowinv = (float*)(P + (size_t)32768 * 512);  // [32768] fp32

  mt_kernel<<<dim3(8, 8), 256, 0, stream>>>(Wq, binding, MT);
  tr_kernel<<<dim3(16, 8), 256, 0, stream>>>(symbols, symT);
  score_kernel<<<512, 512, 0, stream>>>(inp, MT, P, rowinv);
  pv_kernel<<<2048, 256, 0, stream>>>(P, symT, rowinv, out);
}